// Round 5
// baseline (19.789 us; speedup 1.0000x reference)
//
#include <hip/hip_runtime.h>
#include <hip/hip_bf16.h>

// DenseKAN fused: out[b,o] = sum_i [ sum_k bases[b,i,k]*W[i,k,o] + silu(x[b,i]) ] * S[i,o] + bias[o]
// B=4096, D=128, U=128, cubic B-spline, 12 uniform knots -2.2..2.2 (h=0.4), x in [0,1).
// GEMM view: A(4096 x 1152) @ W2ext(1152 x 128); K = 1024 spline slots + 128 silu slots.
// OUTPUT IS FLOAT32 (reference returns f32) — rounds 1-4 failed only on storing bf16.

typedef __attribute__((ext_vector_type(4))) float f32x4;
typedef __attribute__((ext_vector_type(8))) short vshort8;

__device__ __forceinline__ unsigned short f2bf(float f) {
    union { float f; unsigned u; } v; v.f = f;
    return (unsigned short)((v.u + 0x7FFFu + ((v.u >> 16) & 1u)) >> 16);
}

// ---------------------------------------------------------------------------
// prep: Wf[c][o][kk] (bf16), c<36 chunks of 32 k-slots, o<128 units.
// kglob = c*32+kk. kglob<1024: i=kglob>>3,k=kglob&7 -> W[i][k][o]*S[i][o]
//                  kglob>=1024: i=kglob-1024        -> S[i][o]   (silu slots)
// Fragment-ordered: a B-frag load in kan_main is one contiguous 16B dwordx4.
// ---------------------------------------------------------------------------
__global__ __launch_bounds__(256) void kan_prep(
    const float* __restrict__ Ksp,   // (128,8,128)
    const float* __restrict__ S,     // (128,128)
    unsigned short* __restrict__ Wf) // (36,128,32) bf16
{
    int u = blockIdx.x * 256 + threadIdx.x;   // 0..4607
    int c = u >> 7, o = u & 127;
    vshort8 w[4];
    if (c < 32) {
#pragma unroll
        for (int q = 0; q < 32; ++q) {
            int i = c * 4 + (q >> 3);
            float val = Ksp[(c * 32 + q) * 128 + o] * S[i * 128 + o];
            w[q >> 3][q & 7] = (short)f2bf(val);
        }
    } else {
#pragma unroll
        for (int q = 0; q < 32; ++q) {
            int i = (c - 32) * 32 + q;
            w[q >> 3][q & 7] = (short)f2bf(S[i * 128 + o]);
        }
    }
    vshort8* dst = reinterpret_cast<vshort8*>(Wf + (size_t)u * 32);
    dst[0] = w[0]; dst[1] = w[1]; dst[2] = w[2]; dst[3] = w[3];
}

// ---------------------------------------------------------------------------
// main: 256 blocks x 256 threads; block = 16 batch rows x 128 units.
// 4 waves split the 36 K-chunks. A-frag built in registers (closed-form
// uniform cubic B-spline), B-frags are 16B loads from Wf, 8x mfma 16x16x32.
// C/D mapping: lane(r0,g) reg v holds D[4g+v][16n+r0]  (m89, HW-probe-confirmed r2).
// Epilogue: 4-wave LDS reduce + bias, f32 coalesced store.
// ---------------------------------------------------------------------------
__global__ __launch_bounds__(256) void kan_main(
    const float* __restrict__ x,          // (4096,128)
    const unsigned short* __restrict__ Wf,// (36,128,32) bf16
    const float* __restrict__ bias,       // (128)
    float* __restrict__ out)              // (4096,128) f32
{
    const int PAD = 132;
    __shared__ float x_lds[16 * PAD];
    __shared__ float sl_lds[16 * PAD];
    __shared__ float part[4 * 16 * PAD];

    const int tid = threadIdx.x;
    const int rb = blockIdx.x * 16;

    // ---- stage x + silu(x) into LDS (coalesced float4) ----
#pragma unroll
    for (int q = 0; q < 2; ++q) {
        int f4 = tid + q * 256;
        int row = f4 >> 5, c4 = f4 & 31;
        float4 v = reinterpret_cast<const float4*>(x + (size_t)(rb + row) * 128)[c4];
        float4 s;
        s.x = v.x / (1.f + __expf(-v.x));
        s.y = v.y / (1.f + __expf(-v.y));
        s.z = v.z / (1.f + __expf(-v.z));
        s.w = v.w / (1.f + __expf(-v.w));
        reinterpret_cast<float4*>(&x_lds[row * PAD])[c4] = v;
        reinterpret_cast<float4*>(&sl_lds[row * PAD])[c4] = s;
    }
    __syncthreads();

    const int w = tid >> 6;
    const int lane = tid & 63;
    const int r0 = lane & 15;              // A row / B col
    const int g = lane >> 4;               // k-group (8 k per group)

    f32x4 acc[8];
#pragma unroll
    for (int n = 0; n < 8; ++n) { f32x4 z = {0.f, 0.f, 0.f, 0.f}; acc[n] = z; }

    for (int t = 0; t < 9; ++t) {
        const int c = w + 4 * t;
        vshort8 af;
        if (t < 8) {
            // spline chunk: i = c*4+g; nonzero bases at slots j-3..j, j in {5,6,7}
            const int i = c * 4 + g;
            const float xv = x_lds[r0 * PAD + i];
            const float tt = (xv + 2.2f) * 2.5f;
            const float jf = floorf(tt);
            const int j = (int)jf;
            const float u = tt - jf;
            const float u2 = u * u, u3 = u2 * u;
            const float n0 = (1.f / 6.f) * (1.f - 3.f * u + 3.f * u2 - u3);
            const float n1 = (1.f / 6.f) * (3.f * u3 - 6.f * u2 + 4.f);
            const float n2 = (1.f / 6.f) * (-3.f * u3 + 3.f * u2 + 3.f * u + 1.f);
            const float n3 = (1.f / 6.f) * u3;
            const bool j5 = (j == 5), j6 = (j == 6);
            const float s2 = j5 ? n0 : 0.f;
            const float s3 = j5 ? n1 : (j6 ? n0 : 0.f);
            const float s4 = j5 ? n2 : (j6 ? n1 : n0);
            const float s5 = j5 ? n3 : (j6 ? n2 : n1);
            const float s6 = j5 ? 0.f : (j6 ? n3 : n2);
            const float s7 = (!j5 && !j6) ? n3 : 0.f;
            af[0] = 0; af[1] = 0;
            af[2] = (short)f2bf(s2);
            af[3] = (short)f2bf(s3);
            af[4] = (short)f2bf(s4);
            af[5] = (short)f2bf(s5);
            af[6] = (short)f2bf(s6);
            af[7] = (short)f2bf(s7);
        } else {
            // silu chunk: A[b][kk] = silu(x[b][(c-32)*32+kk])
            const int i0 = (c - 32) * 32 + 8 * g;
            const float4* sp = reinterpret_cast<const float4*>(&sl_lds[r0 * PAD + i0]);
            const float4 a = sp[0], b = sp[1];
            af[0] = (short)f2bf(a.x); af[1] = (short)f2bf(a.y);
            af[2] = (short)f2bf(a.z); af[3] = (short)f2bf(a.w);
            af[4] = (short)f2bf(b.x); af[5] = (short)f2bf(b.y);
            af[6] = (short)f2bf(b.z); af[7] = (short)f2bf(b.w);
        }

        const unsigned short* bp = Wf + (size_t)c * 4096 + r0 * 32 + 8 * g;
#pragma unroll
        for (int n = 0; n < 8; ++n) {
            vshort8 bf = *reinterpret_cast<const vshort8*>(bp + n * 512);
            acc[n] = __builtin_amdgcn_mfma_f32_16x16x32_bf16(af, bf, acc[n], 0, 0, 0);
        }
    }

    // lane(r0,g) reg v holds D[row=4g+v][col=16n+r0]
#pragma unroll
    for (int n = 0; n < 8; ++n)
#pragma unroll
        for (int v2 = 0; v2 < 4; ++v2)
            part[w * 16 * PAD + (g * 4 + v2) * PAD + n * 16 + r0] = acc[n][v2];
    __syncthreads();

    // ---- reduce 4 waves + bias, f32 store ----
#pragma unroll
    for (int q = 0; q < 8; ++q) {
        int f = tid + q * 256;             // 0..2047
        int row = f >> 7, col = f & 127;
        float s = part[0 * 16 * PAD + row * PAD + col]
                + part[1 * 16 * PAD + row * PAD + col]
                + part[2 * 16 * PAD + row * PAD + col]
                + part[3 * 16 * PAD + row * PAD + col]
                + bias[col];
        out[(size_t)(rb + row) * 128 + col] = s;
    }
}

// ---------------------------------------------------------------------------
// fallback (only if ws_size < Wf): exact scalar f32 path.
// ---------------------------------------------------------------------------
__global__ __launch_bounds__(128) void kan_fallback(
    const float* __restrict__ x, const float* __restrict__ Ksp,
    const float* __restrict__ S, const float* __restrict__ bias,
    float* __restrict__ out)
{
    __shared__ float n_lds[4][128];
    __shared__ int   j_lds[128];
    __shared__ float sil_lds[128];

    const int b = blockIdx.x, o = threadIdx.x;
    {
        const float xv = x[(size_t)b * 128 + o];
        const float tt = (xv + 2.2f) * 2.5f;
        const float jf = floorf(tt);
        const float u = tt - jf;
        const float u2 = u * u, u3 = u2 * u;
        n_lds[0][o] = (1.f / 6.f) * (1.f - 3.f * u + 3.f * u2 - u3);
        n_lds[1][o] = (1.f / 6.f) * (3.f * u3 - 6.f * u2 + 4.f);
        n_lds[2][o] = (1.f / 6.f) * (-3.f * u3 + 3.f * u2 + 3.f * u + 1.f);
        n_lds[3][o] = (1.f / 6.f) * u3;
        j_lds[o] = (int)jf;
        sil_lds[o] = xv / (1.f + __expf(-xv));
    }
    __syncthreads();

    float acc = 0.f;
    for (int i = 0; i < 128; ++i) {
        const float* wp = Ksp + ((size_t)(i * 8) + (j_lds[i] - 3)) * 128 + o;
        float sp = n_lds[0][i] * wp[0]
                 + n_lds[1][i] * wp[128]
                 + n_lds[2][i] * wp[256]
                 + n_lds[3][i] * wp[384];
        acc += (sp + sil_lds[i]) * S[i * 128 + o];
    }
    out[(size_t)b * 128 + o] = acc + bias[o];
}

extern "C" void kernel_launch(void* const* d_in, const int* in_sizes, int n_in,
                              void* d_out, int out_size, void* d_ws, size_t ws_size,
                              hipStream_t stream) {
    // Resolve inputs robustly: in_sizes may be element counts or bytes.
    int div = 1;
    for (int i = 0; i < n_in; ++i)
        if (in_sizes[i] == 2097152) { div = 4; break; }   // bytes mode detected
    const float *x = nullptr, *Ksp = nullptr, *S = nullptr, *bias = nullptr;
    for (int i = 0; i < n_in; ++i) {
        switch (in_sizes[i] / div) {
            case 4096 * 128:    x    = (const float*)d_in[i]; break;
            case 128 * 8 * 128: Ksp  = (const float*)d_in[i]; break;
            case 128 * 128:     S    = (const float*)d_in[i]; break;
            case 128:           bias = (const float*)d_in[i]; break;
        }
    }
    if (!x || !Ksp || !S || !bias) {   // fallback: dict order
        x = (const float*)d_in[0]; Ksp = (const float*)d_in[1];
        S = (const float*)d_in[2]; bias = (const float*)d_in[3];
    }
    float* out = (float*)d_out;

    const size_t wf_bytes = (size_t)36 * 128 * 32 * sizeof(unsigned short); // 288 KB
    if (ws_size >= wf_bytes) {
        unsigned short* Wf = (unsigned short*)d_ws;
        kan_prep<<<18, 256, 0, stream>>>(Ksp, S, Wf);
        kan_main<<<256, 256, 0, stream>>>(x, Wf, bias, out);
    } else {
        kan_fallback<<<4096, 128, 0, stream>>>(x, Ksp, S, bias, out);
    }
}

// Round 6
// 16.238 us; speedup vs baseline: 1.2187x; 1.2187x over previous
//
#include <hip/hip_runtime.h>
#include <hip/hip_bf16.h>

// DenseKAN fused: out[b,o] = sum_i [ sum_k bases[b,i,k]*W[i,k,o] + silu(x[b,i]) ] * S[i,o] + bias[o]
// B=4096, D=128, U=128, cubic B-spline, 12 uniform knots -2.2..2.2 (h=0.4), x in [0,1).
// GEMM view: A(4096 x 1152) @ W2ext(1152 x 128); K = 1024 spline + 128 silu slots.
// Output f32. Wf[c][o][kk] bf16 staged in d_ws (prep), consumed fragment-contiguous (main).
//
// R6: kan_main 256->512 blocks (16 rows x 64-unit half; 2 blocks/CU for latency hiding),
//     kan_prep 18->72 blocks (thread = (c,o,kk-quad), 9-load chain instead of 64).

typedef __attribute__((ext_vector_type(4))) float f32x4;
typedef __attribute__((ext_vector_type(8))) short vshort8;

__device__ __forceinline__ unsigned short f2bf(float f) {
    union { float f; unsigned u; } v; v.f = f;
    return (unsigned short)((v.u + 0x7FFFu + ((v.u >> 16) & 1u)) >> 16);
}

// ---------------------------------------------------------------------------
// prep: Wf[c][o][kk] (bf16): kglob=c*32+kk; kglob<1024 -> W[i][k][o]*S[i][o]
// (i=kglob>>3,k=kglob&7); kglob>=1024 -> S[kglob-1024][o] (silu slots).
// 72 blocks x 256. Thread u -> (c = u>>9, q = (u>>7)&3, o = u&127), 8 kk values.
// Loads coalesced over o; one vshort8 (16B) store.
// ---------------------------------------------------------------------------
__global__ __launch_bounds__(256) void kan_prep(
    const float* __restrict__ Ksp,   // (128,8,128)
    const float* __restrict__ S,     // (128,128)
    unsigned short* __restrict__ Wf) // (36,128,32) bf16
{
    const int u = blockIdx.x * 256 + threadIdx.x;   // 0..18431
    const int c = u >> 9;
    const int q = (u >> 7) & 3;
    const int o = u & 127;
    vshort8 w;
    if (c < 32) {
        const int i = c * 4 + q;                     // q*8+e all share i (e<8)
        const float s = S[i * 128 + o];
#pragma unroll
        for (int e = 0; e < 8; ++e)
            w[e] = (short)f2bf(Ksp[(size_t)(c * 32 + q * 8 + e) * 128 + o] * s);
    } else {
#pragma unroll
        for (int e = 0; e < 8; ++e) {
            const int i = (c - 32) * 32 + q * 8 + e;
            w[e] = (short)f2bf(S[i * 128 + o]);
        }
    }
    *reinterpret_cast<vshort8*>(Wf + (size_t)c * 4096 + o * 32 + q * 8) = w;
}

// ---------------------------------------------------------------------------
// main: 512 blocks x 256. Block = 16 batch rows x 64 units (bid&1 selects half).
// 4 waves split the 36 K-chunks. A-frag built in registers (closed-form
// uniform cubic B-spline; lane r0 = row, g = k-group -> i = c*4+g).
// B-frags: 16B loads from Wf. 4x mfma 16x16x32 per chunk.
// C/D: lane(r0,g) reg v = D[4g+v][16n+r0] (m89; HW-probe-confirmed r2).
// ---------------------------------------------------------------------------
__global__ __launch_bounds__(256) void kan_main(
    const float* __restrict__ x,          // (4096,128)
    const unsigned short* __restrict__ Wf,// (36,128,32) bf16
    const float* __restrict__ bias,       // (128)
    float* __restrict__ out)              // (4096,128) f32
{
    const int PAD = 132;    // x/sl row stride (floats)
    const int CPAD = 68;    // part row stride (floats)
    __shared__ float x_lds[16 * PAD];
    __shared__ float sl_lds[16 * PAD];
    __shared__ float part[4 * 16 * CPAD];

    const int tid = threadIdx.x;
    const int rb = (blockIdx.x >> 1) * 16;
    const int ob = (blockIdx.x & 1) * 64;

    // ---- stage x + silu(x), 16 rows x 128 (coalesced float4) ----
#pragma unroll
    for (int q = 0; q < 2; ++q) {
        int f4 = tid + q * 256;            // 0..511
        int row = f4 >> 5, c4 = f4 & 31;
        float4 v = reinterpret_cast<const float4*>(x + (size_t)(rb + row) * 128)[c4];
        float4 s;
        s.x = v.x / (1.f + __expf(-v.x));
        s.y = v.y / (1.f + __expf(-v.y));
        s.z = v.z / (1.f + __expf(-v.z));
        s.w = v.w / (1.f + __expf(-v.w));
        reinterpret_cast<float4*>(&x_lds[row * PAD])[c4] = v;
        reinterpret_cast<float4*>(&sl_lds[row * PAD])[c4] = s;
    }
    __syncthreads();

    const int w = tid >> 6;
    const int lane = tid & 63;
    const int r0 = lane & 15;              // A row / D col-within-frag
    const int g = lane >> 4;               // k-group (8 k per group)

    f32x4 acc[4];
#pragma unroll
    for (int n = 0; n < 4; ++n) { f32x4 z = {0.f, 0.f, 0.f, 0.f}; acc[n] = z; }

    for (int t = 0; t < 9; ++t) {
        const int c = w + 4 * t;           // this wave's K-chunk
        vshort8 af;
        if (t < 8) {
            // spline chunk: i = c*4+g; nonzero bases at slots j-3..j, j in {5,6,7}
            const int i = c * 4 + g;
            const float xv = x_lds[r0 * PAD + i];
            const float tt = (xv + 2.2f) * 2.5f;
            const float jf = floorf(tt);
            const int j = (int)jf;
            const float u = tt - jf;
            const float u2 = u * u, u3 = u2 * u;
            const float n0 = (1.f / 6.f) * (1.f - 3.f * u + 3.f * u2 - u3);
            const float n1 = (1.f / 6.f) * (3.f * u3 - 6.f * u2 + 4.f);
            const float n2 = (1.f / 6.f) * (-3.f * u3 + 3.f * u2 + 3.f * u + 1.f);
            const float n3 = (1.f / 6.f) * u3;
            const bool j5 = (j == 5), j6 = (j == 6);
            const float s2 = j5 ? n0 : 0.f;
            const float s3 = j5 ? n1 : (j6 ? n0 : 0.f);
            const float s4 = j5 ? n2 : (j6 ? n1 : n0);
            const float s5 = j5 ? n3 : (j6 ? n2 : n1);
            const float s6 = j5 ? 0.f : (j6 ? n3 : n2);
            const float s7 = (!j5 && !j6) ? n3 : 0.f;
            af[0] = 0; af[1] = 0;
            af[2] = (short)f2bf(s2);
            af[3] = (short)f2bf(s3);
            af[4] = (short)f2bf(s4);
            af[5] = (short)f2bf(s5);
            af[6] = (short)f2bf(s6);
            af[7] = (short)f2bf(s7);
        } else {
            // silu chunk: A[b][kk] = silu(x[b][(c-32)*32+kk])
            const int i0 = (c - 32) * 32 + 8 * g;
            const float4* sp = reinterpret_cast<const float4*>(&sl_lds[r0 * PAD + i0]);
            const float4 a = sp[0], b = sp[1];
            af[0] = (short)f2bf(a.x); af[1] = (short)f2bf(a.y);
            af[2] = (short)f2bf(a.z); af[3] = (short)f2bf(a.w);
            af[4] = (short)f2bf(b.x); af[5] = (short)f2bf(b.y);
            af[6] = (short)f2bf(b.z); af[7] = (short)f2bf(b.w);
        }

        // B cols = units ob + 16n + r0; frag base (ob+r0), stride 16 units = 512 shorts
        const unsigned short* bp = Wf + (size_t)c * 4096 + (ob + r0) * 32 + 8 * g;
#pragma unroll
        for (int n = 0; n < 4; ++n) {
            vshort8 bf = *reinterpret_cast<const vshort8*>(bp + n * 512);
            acc[n] = __builtin_amdgcn_mfma_f32_16x16x32_bf16(af, bf, acc[n], 0, 0, 0);
        }
    }

    // lane(r0,g) reg v holds D[row=4g+v][col=16n+r0]
#pragma unroll
    for (int n = 0; n < 4; ++n)
#pragma unroll
        for (int v2 = 0; v2 < 4; ++v2)
            part[w * 16 * CPAD + (g * 4 + v2) * CPAD + n * 16 + r0] = acc[n][v2];
    __syncthreads();

    // ---- reduce 4 waves + bias, f32 store (64-wide rows, coalesced) ----
#pragma unroll
    for (int q = 0; q < 4; ++q) {
        int f = tid + q * 256;             // 0..1023
        int row = f >> 6, col = f & 63;
        float s = part[0 * 16 * CPAD + row * CPAD + col]
                + part[1 * 16 * CPAD + row * CPAD + col]
                + part[2 * 16 * CPAD + row * CPAD + col]
                + part[3 * 16 * CPAD + row * CPAD + col]
                + bias[ob + col];
        out[(size_t)(rb + row) * 128 + ob + col] = s;
    }
}

// ---------------------------------------------------------------------------
// fallback (only if ws too small): exact scalar f32 path.
// ---------------------------------------------------------------------------
__global__ __launch_bounds__(128) void kan_fallback(
    const float* __restrict__ x, const float* __restrict__ Ksp,
    const float* __restrict__ S, const float* __restrict__ bias,
    float* __restrict__ out)
{
    __shared__ float n_lds[4][128];
    __shared__ int   j_lds[128];
    __shared__ float sil_lds[128];

    const int b = blockIdx.x, o = threadIdx.x;
    {
        const float xv = x[(size_t)b * 128 + o];
        const float tt = (xv + 2.2f) * 2.5f;
        const float jf = floorf(tt);
        const float u = tt - jf;
        const float u2 = u * u, u3 = u2 * u;
        n_lds[0][o] = (1.f / 6.f) * (1.f - 3.f * u + 3.f * u2 - u3);
        n_lds[1][o] = (1.f / 6.f) * (3.f * u3 - 6.f * u2 + 4.f);
        n_lds[2][o] = (1.f / 6.f) * (-3.f * u3 + 3.f * u2 + 3.f * u + 1.f);
        n_lds[3][o] = (1.f / 6.f) * u3;
        j_lds[o] = (int)jf;
        sil_lds[o] = xv / (1.f + __expf(-xv));
    }
    __syncthreads();

    float acc = 0.f;
    for (int i = 0; i < 128; ++i) {
        const float* wp = Ksp + ((size_t)(i * 8) + (j_lds[i] - 3)) * 128 + o;
        float sp = n_lds[0][i] * wp[0]
                 + n_lds[1][i] * wp[128]
                 + n_lds[2][i] * wp[256]
                 + n_lds[3][i] * wp[384];
        acc += (sp + sil_lds[i]) * S[i * 128 + o];
    }
    out[(size_t)b * 128 + o] = acc + bias[o];
}

extern "C" void kernel_launch(void* const* d_in, const int* in_sizes, int n_in,
                              void* d_out, int out_size, void* d_ws, size_t ws_size,
                              hipStream_t stream) {
    // Resolve inputs robustly (element counts or bytes).
    int div = 1;
    for (int i = 0; i < n_in; ++i)
        if (in_sizes[i] == 2097152) { div = 4; break; }
    const float *x = nullptr, *Ksp = nullptr, *S = nullptr, *bias = nullptr;
    for (int i = 0; i < n_in; ++i) {
        switch (in_sizes[i] / div) {
            case 4096 * 128:    x    = (const float*)d_in[i]; break;
            case 128 * 8 * 128: Ksp  = (const float*)d_in[i]; break;
            case 128 * 128:     S    = (const float*)d_in[i]; break;
            case 128:           bias = (const float*)d_in[i]; break;
        }
    }
    if (!x || !Ksp || !S || !bias) {
        x = (const float*)d_in[0]; Ksp = (const float*)d_in[1];
        S = (const float*)d_in[2]; bias = (const float*)d_in[3];
    }
    float* out = (float*)d_out;

    const size_t wf_bytes = (size_t)36 * 128 * 32 * sizeof(unsigned short); // 288 KB
    if (ws_size >= wf_bytes) {
        unsigned short* Wf = (unsigned short*)d_ws;
        kan_prep<<<72, 256, 0, stream>>>(Ksp, S, Wf);
        kan_main<<<512, 256, 0, stream>>>(x, Wf, bias, out);
    } else {
        kan_fallback<<<4096, 128, 0, stream>>>(x, Ksp, S, bias, out);
    }
}